// Round 1
// baseline (118.861 us; speedup 1.0000x reference)
//
#include <hip/hip_runtime.h>
#include <math.h>

// MatchNet: 4-layer tanh MLP (6->20->20->20->8) + 150-iter PDHG QP solve.
// One thread per batch sample; all PDHG state in registers; S hardcoded.

#define NITERS 150

__device__ __forceinline__ float ftanh(float a) {
    // tanh(a) = 1 - 2/(e^{2a}+1); rcp approx is ~1 ulp, fine vs 1.8e-2 tol
    float e = __expf(2.0f * a);
    return fmaf(-2.0f, __builtin_amdgcn_rcpf(e + 1.0f), 1.0f);
}

__global__ __launch_bounds__(64) void matchnet_kernel(
    const float* __restrict__ X,
    const float* __restrict__ W1, const float* __restrict__ b1,
    const float* __restrict__ W2, const float* __restrict__ b2,
    const float* __restrict__ W3, const float* __restrict__ b3,
    const float* __restrict__ W4, const float* __restrict__ b4,
    float* __restrict__ out, int B)
{
    // ---- stage all weights in LDS (1148 floats = 4.6 KB) ----
    __shared__ float sw[1148];
    const int t = threadIdx.x;
    for (int i = t; i < 120; i += 64) sw[i]        = W1[i];
    for (int i = t; i < 20;  i += 64) sw[120 + i]  = b1[i];
    for (int i = t; i < 400; i += 64) sw[140 + i]  = W2[i];
    for (int i = t; i < 20;  i += 64) sw[540 + i]  = b2[i];
    for (int i = t; i < 400; i += 64) sw[560 + i]  = W3[i];
    for (int i = t; i < 20;  i += 64) sw[960 + i]  = b3[i];
    for (int i = t; i < 160; i += 64) sw[980 + i]  = W4[i];
    if (t < 8) sw[1140 + t] = b4[t];
    __syncthreads();

    const int gid = blockIdx.x * 64 + t;
    if (gid >= B) return;

    const float TAU = 0.9f / sqrtf(26.0f);   // L = sqrt(sum(S*S)+ns) = sqrt(18+8)
    const float SIG = TAU;

    // ---- load sample (6 floats; doubles as QP rhs b) ----
    float zin[6];
    {
        const float2* xp = (const float2*)(X + (size_t)gid * 6);
        float2 p0 = xp[0], p1 = xp[1], p2 = xp[2];
        zin[0] = p0.x; zin[1] = p0.y; zin[2] = p1.x;
        zin[3] = p1.y; zin[4] = p2.x; zin[5] = p2.y;
    }

    // ---- MLP ----
    float h1[20];
#pragma unroll
    for (int j = 0; j < 20; ++j) {
        float a = sw[120 + j];
#pragma unroll
        for (int k = 0; k < 6; ++k) a = fmaf(sw[j*6 + k], zin[k], a);
        h1[j] = ftanh(a);
    }
    float h2[20];
#pragma unroll
    for (int j = 0; j < 20; ++j) {
        float a = sw[540 + j];
#pragma unroll
        for (int k = 0; k < 20; ++k) a = fmaf(sw[140 + j*20 + k], h1[k], a);
        h2[j] = ftanh(a);
    }
    float h3[20];
#pragma unroll
    for (int j = 0; j < 20; ++j) {
        float a = sw[960 + j];
#pragma unroll
        for (int k = 0; k < 20; ++k) a = fmaf(sw[560 + j*20 + k], h2[k], a);
        h3[j] = ftanh(a);
    }
    float z[8];
#pragma unroll
    for (int j = 0; j < 8; ++j) {
        float a = sw[1140 + j];
#pragma unroll
        for (int k = 0; k < 20; ++k) a = fmaf(sw[980 + j*20 + k], h3[k], a);
        z[j] = ftanh(a);
    }

    // ---- PDHG: max w.x - ||x-z||  s.t. x>=0, Sx<=b (b = zin, w = 1) ----
    float x[8], l2[8], tz[8];
#pragma unroll
    for (int j = 0; j < 8; ++j) { x[j] = fmaxf(z[j], 0.0f); l2[j] = 0.0f; tz[j] = TAU - z[j]; }
    float l1[6], sb[6];
#pragma unroll
    for (int i = 0; i < 6; ++i) { l1[i] = 0.0f; sb[i] = SIG * zin[i]; }

#pragma unroll 1
    for (int it = 0; it < NITERS; ++it) {
        // S^T l1 (S hardcoded; columns {0,3},{1,4},{2,5},{0,1,5},{2,3,5},{0,3},{1,4},{2,4})
        float t03 = l1[0] + l1[3];
        float t14 = l1[1] + l1[4];
        float t25 = l1[2] + l1[5];
        float st[8];
        st[0] = t03; st[1] = t14; st[2] = t25;
        st[3] = (l1[0] + l1[1]) + l1[5];
        st[4] = (l1[2] + l1[3]) + l1[5];
        st[5] = t03; st[6] = t14;
        st[7] = l1[2] + l1[4];

        // v = (x - tau*(S^T l1 - l2)) + tau*w - z
        float v[8];
#pragma unroll
        for (int j = 0; j < 8; ++j)
            v[j] = fmaf(-TAU, st[j] - l2[j], x[j]) + tz[j];

        float n01 = fmaf(v[0], v[0], v[1]*v[1]);
        float n23 = fmaf(v[2], v[2], v[3]*v[3]);
        float n45 = fmaf(v[4], v[4], v[5]*v[5]);
        float n67 = fmaf(v[6], v[6], v[7]*v[7]);
        float nv2 = (n01 + n23) + (n45 + n67);
        // scale = max(1 - tau/||v||, 0); rsq(0)=inf -> scale=0 matches ref clamp
        float scale = fmaxf(fmaf(-TAU, __builtin_amdgcn_rsqf(nv2), 1.0f), 0.0f);

        float xb[8];
#pragma unroll
        for (int j = 0; j < 8; ++j) {
            float xn = fmaf(scale, v[j], z[j]);
            xb[j] = fmaf(2.0f, xn, -x[j]);
            x[j] = xn;
            l2[j] = fmaxf(fmaf(-SIG, xb[j], l2[j]), 0.0f);
        }

        // S xbar (rows {0,3,5},{1,3,6},{2,4,7},{0,4,5},{1,6,7},{2,3,4})
        float r0 = (xb[0] + xb[3]) + xb[5];
        float r1 = (xb[1] + xb[3]) + xb[6];
        float r2 = (xb[2] + xb[4]) + xb[7];
        float r3 = (xb[0] + xb[4]) + xb[5];
        float r4 = (xb[1] + xb[6]) + xb[7];
        float r5 = (xb[2] + xb[3]) + xb[4];
        l1[0] = fmaxf(fmaf(SIG, r0, l1[0]) - sb[0], 0.0f);
        l1[1] = fmaxf(fmaf(SIG, r1, l1[1]) - sb[1], 0.0f);
        l1[2] = fmaxf(fmaf(SIG, r2, l1[2]) - sb[2], 0.0f);
        l1[3] = fmaxf(fmaf(SIG, r3, l1[3]) - sb[3], 0.0f);
        l1[4] = fmaxf(fmaf(SIG, r4, l1[4]) - sb[4], 0.0f);
        l1[5] = fmaxf(fmaf(SIG, r5, l1[5]) - sb[5], 0.0f);
    }

    float4* op = (float4*)(out + (size_t)gid * 8);
    op[0] = make_float4(x[0], x[1], x[2], x[3]);
    op[1] = make_float4(x[4], x[5], x[6], x[7]);
}

extern "C" void kernel_launch(void* const* d_in, const int* in_sizes, int n_in,
                              void* d_out, int out_size, void* d_ws, size_t ws_size,
                              hipStream_t stream) {
    const float* X  = (const float*)d_in[0];
    const float* W1 = (const float*)d_in[1];
    const float* b1 = (const float*)d_in[2];
    const float* W2 = (const float*)d_in[3];
    const float* b2 = (const float*)d_in[4];
    const float* W3 = (const float*)d_in[5];
    const float* b3 = (const float*)d_in[6];
    const float* W4 = (const float*)d_in[7];
    const float* b4 = (const float*)d_in[8];
    float* out = (float*)d_out;
    const int B = in_sizes[0] / 6;
    const int blocks = (B + 63) / 64;
    hipLaunchKernelGGL(matchnet_kernel, dim3(blocks), dim3(64), 0, stream,
                       X, W1, b1, W2, b2, W3, b3, W4, b4, out, B);
}